// Round 4
// baseline (99.435 us; speedup 1.0000x reference)
//
#include <hip/hip_runtime.h>
#include <hip/hip_bf16.h>
#include <math.h>

#define B_  4096u
#define N_  8192
#define D_  128
#define M_  8190u          // negatives per logits row = 2B-2
#define SB_ 25159680u      // S_B = B*(2B-2) - B*(B-1)/2
#define NT_ 2080           // number of upper-triangle 128x128 tiles

typedef __attribute__((ext_vector_type(8))) short bf16x8;
typedef __attribute__((ext_vector_type(4))) float f32x4;
typedef __attribute__((ext_vector_type(4))) short short4v;

static __device__ __forceinline__ short f2b(float x) {
  __hip_bfloat16 h = __float2bfloat16(x);
  union { __hip_bfloat16 h; short s; } u; u.h = h; return u.s;
}
// cumulative flat-count of strict-upper (minus positives) elements before row i
static __device__ __forceinline__ unsigned rowS(unsigned i) {
  if (i <= B_) return i * (2u * B_ - 2u) - (i * (i - 1u)) / 2u;
  unsigned d = i - B_;
  return SB_ + d * (B_ - 1u) - (d * (d - 1u)) / 2u;
}

// ---------------------------------------------------------------------------
// Kernel A: normalize rows of reps=[zjs;zis] -> bf16 nb[row][k]; also build
// per-row bucket threshold table Trow[i]: element (i,j) goes to bucket rlo(i)
// iff j < Trow[i], else rlo(i)+1.
// ---------------------------------------------------------------------------
__global__ __launch_bounds__(256) void nt_norm(
    const float* __restrict__ zis, const float* __restrict__ zjs,
    short* __restrict__ nb, unsigned* __restrict__ Trow) {
  const int t   = threadIdx.x;
  const int row = blockIdx.x * 8 + (t >> 5);
  const int c   = t & 31;
  const float* src = (row < (int)B_) ? (zjs + (size_t)row * D_)
                                     : (zis + (size_t)(row - (int)B_) * D_);
  float4 v = *(const float4*)(src + c * 4);
  float s = v.x * v.x + v.y * v.y + v.z * v.z + v.w * v.w;
  #pragma unroll
  for (int m = 16; m >= 1; m >>= 1) s += __shfl_xor(s, m, 32);
  float rn = 1.0f / fmaxf(sqrtf(s), 1e-8f);
  short4v o;
  o[0] = f2b(v.x * rn); o[1] = f2b(v.y * rn);
  o[2] = f2b(v.z * rn); o[3] = f2b(v.w * rn);
  *(short4v*)(nb + (size_t)row * D_ + c * 4) = o;

  if (t < 8) {
    unsigned i   = (unsigned)(blockIdx.x * 8 + t);
    unsigned S   = rowS(i);
    unsigned rlo = S / M_;
    unsigned Sh  = (rlo + 1u) * M_;
    unsigned jt  = Sh - S + i + 1u;                    // flip col (no skip)
    Trow[i] = jt + ((i < B_ && jt > i + B_) ? 1u : 0u);
  }
}

// ---------------------------------------------------------------------------
// Kernel B: upper-tri Gram via bf16 MFMA, fragments DIRECT from L2 (no LDS
// staging, no barrier in compute). 128x128 tile, 4 waves 2x2, 4x4 frags.
// Epilogue: threshold-bucket sums, LDS transpose-reduce, plain float2 stores.
// Positive-carrier tiles (bj==bi+32) also store posl. No atomics anywhere.
// ---------------------------------------------------------------------------
__global__ __launch_bounds__(256) void nt_gemm(
    const short* __restrict__ nb, const unsigned* __restrict__ Trow,
    float2* __restrict__ part, float* __restrict__ posl) {
  // linear upper-triangle decode: t0(bi) = bi*64 - bi*(bi-1)/2
  const int tb = (int)blockIdx.x;
  int bi = (int)((129.0f - sqrtf(16641.0f - 8.0f * (float)tb)) * 0.5f);
  while (bi > 0 && tb < bi * 64 - bi * (bi - 1) / 2) --bi;
  while (tb >= (bi + 1) * 64 - (bi + 1) * bi / 2) ++bi;
  const int bj = bi + (tb - (bi * 64 - bi * (bi - 1) / 2));

  const int t    = threadIdx.x;
  const int lane = t & 63, wave = t >> 6;
  const int li   = lane & 15, hi = lane >> 4;
  const int wrow = (wave >> 1) * 64, wcol = (wave & 1) * 64;
  const int i0   = bi * 128, j0 = bj * 128;

  const short* gA = nb + (size_t)(i0 + wrow) * D_;
  const short* gB = nb + (size_t)(j0 + wcol) * D_;

  f32x4 acc[4][4];
  #pragma unroll
  for (int m = 0; m < 4; ++m)
    #pragma unroll
    for (int n = 0; n < 4; ++n) acc[m][n] = (f32x4){0.f, 0.f, 0.f, 0.f};

  #pragma unroll
  for (int ks = 0; ks < 4; ++ks) {
    const int koff = ks * 32 + hi * 8;
    bf16x8 af[4], bfr[4];
    #pragma unroll
    for (int m = 0; m < 4; ++m)
      af[m] = *(const bf16x8*)(gA + (m * 16 + li) * D_ + koff);
    #pragma unroll
    for (int n = 0; n < 4; ++n)
      bfr[n] = *(const bf16x8*)(gB + (n * 16 + li) * D_ + koff);
    #pragma unroll
    for (int m = 0; m < 4; ++m)
      #pragma unroll
      for (int n = 0; n < 4; ++n)
        acc[m][n] = __builtin_amdgcn_mfma_f32_16x16x32_bf16(
            af[m], bfr[n], acc[m][n], 0, 0, 0);
  }

  // ---- epilogue ----
  __shared__ float2 sred[4][64][17];   // [wave][local row 0..63][li], padded
  const unsigned jb = (unsigned)(j0 + wcol + li);
  const bool interior = (bj != bi) && (bj != bi + 32);

  #pragma unroll
  for (int m = 0; m < 4; ++m) {
    const uint4 T4 = *(const uint4*)(Trow + i0 + wrow + m * 16 + hi * 4);
    const unsigned Ts[4] = {T4.x, T4.y, T4.z, T4.w};
    #pragma unroll
    for (int rg = 0; rg < 4; ++rg) {
      const unsigned i = (unsigned)(i0 + wrow + m * 16 + hi * 4 + rg);
      const unsigned T = Ts[rg];
      float s0 = 0.f, s1 = 0.f;
      if (interior) {
        #pragma unroll
        for (int n = 0; n < 4; ++n) {
          float e = __expf(2.0f * acc[m][n][rg]);
          if (jb + n * 16 < T) s0 += e; else s1 += e;
        }
      } else {
        #pragma unroll
        for (int n = 0; n < 4; ++n) {
          const unsigned j = jb + n * 16;
          const bool ispos = (i < B_) && (j == i + B_);
          if (ispos) posl[i] = 2.0f * acc[m][n][rg];
          if ((j > i) && !ispos) {
            float e = __expf(2.0f * acc[m][n][rg]);
            if (j < T) s0 += e; else s1 += e;
          }
        }
      }
      sred[wave][m * 16 + hi * 4 + rg][li] = make_float2(s0, s1);
    }
  }
  __syncthreads();

  {  // transpose-reduce: one thread per (wave, local row)
    const int uw = t >> 6, ur = t & 63;
    float2 s = make_float2(0.f, 0.f);
    #pragma unroll
    for (int l = 0; l < 16; ++l) {
      float2 v = sred[uw][ur][l];
      s.x += v.x; s.y += v.y;
    }
    part[((size_t)tb * 2 + (uw & 1)) * 128 + ((uw >> 1) * 64 + ur)] = s;
  }
}

// ---------------------------------------------------------------------------
// Kernel C: per-row reduction of partials. One block per bi (coalesced).
// ---------------------------------------------------------------------------
__global__ __launch_bounds__(256) void nt_rowreduce(
    const float2* __restrict__ part, float2* __restrict__ rowsum) {
  __shared__ float2 red[256];
  const int bi   = (int)blockIdx.x;          // 0..63
  const int t    = threadIdx.x;
  const int lrow = t & 127, sh = t >> 7;
  const int t0   = bi * 64 - bi * (bi - 1) / 2;
  const int nsl  = 2 * (64 - bi);
  float2 s = make_float2(0.f, 0.f);
  for (int sl = sh; sl < nsl; sl += 2) {
    float2 v = part[((size_t)t0 * 2 + sl) * 128 + lrow];
    s.x += v.x; s.y += v.y;
  }
  red[t] = s;
  __syncthreads();
  if (t < 128) {
    float2 v = red[t + 128];
    s = red[t];
    s.x += v.x; s.y += v.y;
    rowsum[bi * 128 + lrow] = s;
  }
}

// ---------------------------------------------------------------------------
// Kernel D: finalize (one block). Build E buckets in LDS, then loss.
// ---------------------------------------------------------------------------
__global__ __launch_bounds__(256) void nt_finalize(
    const float2* __restrict__ rowsum, const float* __restrict__ posl,
    float* __restrict__ out) {
  __shared__ float Eb[4104];     // 4096 buckets + slack (rlo up to 4096)
  __shared__ double red[256];
  const int t = threadIdx.x;

  for (int r = t; r < 4104; r += 256)
    Eb[r] = (r < 4096) ? __expf(posl[r]) : 0.f;
  __syncthreads();

  for (int i = t; i < (int)N_; i += 256) {
    const unsigned S   = rowS((unsigned)i);
    const unsigned rlo = S / M_;
    float2 v = rowsum[i];
    atomicAdd(&Eb[rlo], v.x);        // LDS atomics (on-CU, cheap)
    atomicAdd(&Eb[rlo + 1], v.y);
  }
  __syncthreads();

  double s = 0.0;
  for (int r = t; r < (int)B_; r += 256)
    s += (double)(logf(Eb[r]) - posl[r]);
  red[t] = s;
  __syncthreads();
  for (int m = 128; m > 0; m >>= 1) {
    if (t < m) red[t] += red[t + m];
    __syncthreads();
  }
  if (t == 0) out[0] = (float)(red[0] / (double)B_);
}

// ---------------------------------------------------------------------------
extern "C" void kernel_launch(void* const* d_in, const int* in_sizes, int n_in,
                              void* d_out, int out_size, void* d_ws, size_t ws_size,
                              hipStream_t stream) {
  const float* zis = (const float*)d_in[0];
  const float* zjs = (const float*)d_in[1];
  float* out = (float*)d_out;

  char* ws = (char*)d_ws;
  short*    nb     = (short*)ws;                          // 2 MB
  unsigned* Trow   = (unsigned*)(ws + 2097152);           // 32 KB
  float*    posl   = (float*)(ws + 2097152 + 32768);      // 16 KB
  float2*   part   = (float2*)(ws + 2097152 + 32768 + 16384);  // 4.26 MB
  float2*   rowsum = (float2*)(ws + 2097152 + 32768 + 16384 + 4259840); // 64 KB

  nt_norm     <<<dim3(N_ / 8), 256, 0, stream>>>(zis, zjs, nb, Trow);
  nt_gemm     <<<dim3(NT_),    256, 0, stream>>>(nb, Trow, part, posl);
  nt_rowreduce<<<dim3(64),     256, 0, stream>>>(part, rowsum);
  nt_finalize <<<dim3(1),      256, 0, stream>>>(rowsum, posl, out);
}

// Round 5
// 80.049 us; speedup vs baseline: 1.2422x; 1.2422x over previous
//
#include <hip/hip_runtime.h>
#include <hip/hip_bf16.h>
#include <math.h>

#define B_  4096u
#define N_  8192
#define D_  128
#define M_  8190u          // negatives per logits row = 2B-2
#define SB_ 25159680u      // S_B = B*(2B-2) - B*(B-1)/2
#define NT2_ 1056          // upper-tri 128x256 tiles: sum_{bi=0..63}(32 - bi/2)

typedef __attribute__((ext_vector_type(8))) short bf16x8;
typedef __attribute__((ext_vector_type(4))) float f32x4;
typedef __attribute__((ext_vector_type(4))) short short4v;

static __device__ __forceinline__ short f2b(float x) {
  __hip_bfloat16 h = __float2bfloat16(x);
  union { __hip_bfloat16 h; short s; } u; u.h = h; return u.s;
}
// cumulative flat-count of strict-upper (minus positives) elements before row i
static __device__ __forceinline__ unsigned rowS(unsigned i) {
  if (i <= B_) return i * (2u * B_ - 2u) - (i * (i - 1u)) / 2u;
  unsigned d = i - B_;
  return SB_ + d * (B_ - 1u) - (d * (d - 1u)) / 2u;
}
// cumulative tile count before row-panel m (128-row panels, 256-col tiles)
static __device__ __forceinline__ int tile0(int m) {
  return 32 * m - (m * m - 2 * m + (m & 1)) / 4;
}

// ---------------------------------------------------------------------------
// Kernel A: normalize rows of reps=[zjs;zis] -> bf16 nb[row][k]; build Trow.
// Element (i,j) goes to bucket rlo(i) iff j < Trow[i], else rlo(i)+1.
// ---------------------------------------------------------------------------
__global__ __launch_bounds__(256) void nt_norm(
    const float* __restrict__ zis, const float* __restrict__ zjs,
    short* __restrict__ nb, unsigned* __restrict__ Trow) {
  const int t   = threadIdx.x;
  const int row = blockIdx.x * 8 + (t >> 5);
  const int c   = t & 31;
  const float* src = (row < (int)B_) ? (zjs + (size_t)row * D_)
                                     : (zis + (size_t)(row - (int)B_) * D_);
  float4 v = *(const float4*)(src + c * 4);
  float s = v.x * v.x + v.y * v.y + v.z * v.z + v.w * v.w;
  #pragma unroll
  for (int m = 16; m >= 1; m >>= 1) s += __shfl_xor(s, m, 32);
  float rn = 1.0f / fmaxf(sqrtf(s), 1e-8f);
  short4v o;
  o[0] = f2b(v.x * rn); o[1] = f2b(v.y * rn);
  o[2] = f2b(v.z * rn); o[3] = f2b(v.w * rn);
  *(short4v*)(nb + (size_t)row * D_ + c * 4) = o;

  if (t < 8) {
    unsigned i   = (unsigned)(blockIdx.x * 8 + t);
    unsigned S   = rowS(i);
    unsigned rlo = S / M_;
    unsigned Sh  = (rlo + 1u) * M_;
    unsigned jt  = Sh - S + i + 1u;
    Trow[i] = jt + ((i < B_ && jt > i + B_) ? 1u : 0u);
  }
}

// ---------------------------------------------------------------------------
// Kernel B: 128x256-tile upper-tri Gram, bf16 MFMA, 8 waves (2x4).
// K=128 as 2x BK=64 LDS-staged via global_load_lds(16B), both-sides XOR
// swizzle (slot ^= row&7). Epilogue: threshold-flag bucket sums, shfl reduce,
// tiny-LDS cross-wave combine, ONE float2 store per (tile,row). No atomics.
// ---------------------------------------------------------------------------
__global__ __launch_bounds__(512, 4) void nt_gemm(
    const short* __restrict__ nb, const unsigned* __restrict__ Trow,
    float2* __restrict__ part, float* __restrict__ posl) {
  // XCD-chunked bijective swizzle: 1056 = 8 * 132
  const int tb = ((int)blockIdx.x & 7) * 132 + ((int)blockIdx.x >> 3);
  // decode tile -> (bi2, bj2):  tile0(m) = 32m - (m^2-2m+(m&1))/4
  int bi2 = (int)(2.0f * (32.0f - sqrtf(fmaxf(0.f, 1024.0f - (float)tb))));
  if (bi2 > 63) bi2 = 63;
  while (bi2 > 0 && tb < tile0(bi2)) --bi2;
  while (tb >= tile0(bi2 + 1)) ++bi2;
  const int jlo = bi2 >> 1;
  const int bj2 = jlo + (tb - tile0(bi2));

  __shared__ short As[128 * 64];        // 16KB
  __shared__ short Bs[256 * 64];        // 32KB
  __shared__ float2 red2[4][128];       // 4KB

  const int t    = threadIdx.x;
  const int lane = t & 63, wave = t >> 6;
  const int li   = lane & 15, hi = lane >> 4;
  const int wr   = wave >> 2, wc = wave & 3;   // 2x4 wave grid
  const int i0   = bi2 * 128, j0 = bj2 * 256;

  const short* gA = nb + (size_t)i0 * D_;
  const short* gB = nb + (size_t)j0 * D_;

  f32x4 acc[4][4];
  #pragma unroll
  for (int m = 0; m < 4; ++m)
    #pragma unroll
    for (int n = 0; n < 4; ++n) acc[m][n] = (f32x4){0.f, 0.f, 0.f, 0.f};

  #pragma unroll
  for (int kh = 0; kh < 2; ++kh) {
    const int kb = kh * 64;   // element offset within row
    // ---- stage A (1024 x 16B units) ----
    #pragma unroll
    for (int it = 0; it < 2; ++it) {
      int e = it * 512 + t;
      int r = e >> 3, s = e & 7, sg = s ^ (r & 7);
      __builtin_amdgcn_global_load_lds(
          (const __attribute__((address_space(1))) void*)(gA + (size_t)r * D_ + kb + sg * 8),
          (__attribute__((address_space(3))) void*)(As + e * 8), 16, 0, 0);
    }
    // ---- stage B (2048 x 16B units) ----
    #pragma unroll
    for (int it = 0; it < 4; ++it) {
      int e = it * 512 + t;
      int r = e >> 3, s = e & 7, sg = s ^ (r & 7);
      __builtin_amdgcn_global_load_lds(
          (const __attribute__((address_space(1))) void*)(gB + (size_t)r * D_ + kb + sg * 8),
          (__attribute__((address_space(3))) void*)(Bs + e * 8), 16, 0, 0);
    }
    __syncthreads();
    // ---- compute 2 ks chunks of K=32 ----
    #pragma unroll
    for (int ks = 0; ks < 2; ++ks) {
      const int sb = ks * 4 + hi;              // 16B slot base 0..7
      const int sw = sb ^ (li & 7);            // swizzled slot
      bf16x8 af[4], bfr[4];
      #pragma unroll
      for (int m = 0; m < 4; ++m) {
        int row = wr * 64 + m * 16 + li;
        af[m] = *(const bf16x8*)(As + row * 64 + sw * 8);
      }
      #pragma unroll
      for (int n = 0; n < 4; ++n) {
        int row = wc * 64 + n * 16 + li;
        bfr[n] = *(const bf16x8*)(Bs + row * 64 + sw * 8);
      }
      #pragma unroll
      for (int m = 0; m < 4; ++m)
        #pragma unroll
        for (int n = 0; n < 4; ++n)
          acc[m][n] = __builtin_amdgcn_mfma_f32_16x16x32_bf16(
              af[m], bfr[n], acc[m][n], 0, 0, 0);
    }
    __syncthreads();
  }

  // ---- epilogue ----
  const bool isdiag = (bj2 == jlo);
  const bool ispost = (bj2 == jlo + 16);
  const unsigned jw0 = (unsigned)(j0 + wc * 64);

  #pragma unroll
  for (int m = 0; m < 4; ++m) {
    const uint4 T4 = *(const uint4*)(Trow + i0 + wr * 64 + m * 16 + hi * 4);
    const unsigned Ts[4] = {T4.x, T4.y, T4.z, T4.w};
    #pragma unroll
    for (int rg = 0; rg < 4; ++rg) {
      const unsigned i = (unsigned)(i0 + wr * 64 + m * 16 + hi * 4 + rg);
      const unsigned T = Ts[rg];
      float s0 = 0.f, s1 = 0.f;
      if (isdiag | ispost) {
        #pragma unroll
        for (int n = 0; n < 4; ++n) {
          const unsigned j = jw0 + n * 16 + (unsigned)li;
          const bool ip = ispost && (j == i + B_);
          if (ip) posl[i] = 2.0f * acc[m][n][rg];
          if ((j > i) && !ip) {
            float e = __expf(2.0f * acc[m][n][rg]);
            if (j < T) s0 += e; else s1 += e;
          }
        }
      } else if ((T > jw0) && (T < jw0 + 64u)) {   // straddle (rare)
        #pragma unroll
        for (int n = 0; n < 4; ++n) {
          const unsigned j = jw0 + n * 16 + (unsigned)li;
          float e = __expf(2.0f * acc[m][n][rg]);
          if (j < T) s0 += e; else s1 += e;
        }
      } else {                                      // uniform bucket
        float s = 0.f;
        #pragma unroll
        for (int n = 0; n < 4; ++n) s += __expf(2.0f * acc[m][n][rg]);
        if (T > jw0) s0 = s; else s1 = s;
      }
      #pragma unroll
      for (int msk = 8; msk >= 1; msk >>= 1) {
        s0 += __shfl_xor(s0, msk, 16);
        s1 += __shfl_xor(s1, msk, 16);
      }
      if (li == 0)
        red2[wc][wr * 64 + m * 16 + hi * 4 + rg] = make_float2(s0, s1);
    }
  }
  __syncthreads();

  if (t < 128) {
    float2 s = make_float2(0.f, 0.f);
    #pragma unroll
    for (int w = 0; w < 4; ++w) {
      float2 v = red2[w][t];
      s.x += v.x; s.y += v.y;
    }
    part[(size_t)tb * 128 + t] = s;
  }
}

// ---------------------------------------------------------------------------
// Kernel C: per-row reduction of partials. One THREAD per sim-row.
// ---------------------------------------------------------------------------
__global__ __launch_bounds__(256) void nt_rowreduce(
    const float2* __restrict__ part, float2* __restrict__ rowsum) {
  const int i = (int)blockIdx.x * 256 + (int)threadIdx.x;   // 0..8191
  const int bi2 = i >> 7, lrow = i & 127;
  const int base = tile0(bi2);
  const int cnt  = 32 - (bi2 >> 1);
  float2 s = make_float2(0.f, 0.f);
  for (int c = 0; c < cnt; ++c) {
    float2 v = part[(size_t)(base + c) * 128 + lrow];
    s.x += v.x; s.y += v.y;
  }
  rowsum[i] = s;
}

// ---------------------------------------------------------------------------
// Kernel D: finalize (one block). Build E buckets in LDS, then loss.
// ---------------------------------------------------------------------------
__global__ __launch_bounds__(256) void nt_finalize(
    const float2* __restrict__ rowsum, const float* __restrict__ posl,
    float* __restrict__ out) {
  __shared__ float Eb[4104];
  __shared__ double red[256];
  const int t = threadIdx.x;

  for (int r = t; r < 4104; r += 256)
    Eb[r] = (r < 4096) ? __expf(posl[r]) : 0.f;
  __syncthreads();

  for (int i = t; i < (int)N_; i += 256) {
    const unsigned S   = rowS((unsigned)i);
    const unsigned rlo = S / M_;
    float2 v = rowsum[i];
    atomicAdd(&Eb[rlo], v.x);
    atomicAdd(&Eb[rlo + 1], v.y);
  }
  __syncthreads();

  double s = 0.0;
  for (int r = t; r < (int)B_; r += 256)
    s += (double)(logf(Eb[r]) - posl[r]);
  red[t] = s;
  __syncthreads();
  for (int m = 128; m > 0; m >>= 1) {
    if (t < m) red[t] += red[t + m];
    __syncthreads();
  }
  if (t == 0) out[0] = (float)(red[0] / (double)B_);
}

// ---------------------------------------------------------------------------
extern "C" void kernel_launch(void* const* d_in, const int* in_sizes, int n_in,
                              void* d_out, int out_size, void* d_ws, size_t ws_size,
                              hipStream_t stream) {
  const float* zis = (const float*)d_in[0];
  const float* zjs = (const float*)d_in[1];
  float* out = (float*)d_out;

  char* ws = (char*)d_ws;
  short*    nb     = (short*)ws;                               // 2 MB
  unsigned* Trow   = (unsigned*)(ws + 2097152);                // 32 KB
  float*    posl   = (float*)(ws + 2097152 + 32768);           // 16 KB
  float2*   part   = (float2*)(ws + 2097152 + 32768 + 16384);  // 1056*128*8 = 1.08 MB
  float2*   rowsum = (float2*)(ws + 2097152 + 32768 + 16384 + 1081344);  // 64 KB

  nt_norm     <<<dim3(N_ / 8), 256, 0, stream>>>(zis, zjs, nb, Trow);
  nt_gemm     <<<dim3(NT2_),   512, 0, stream>>>(nb, Trow, part, posl);
  nt_rowreduce<<<dim3(N_/256), 256, 0, stream>>>(part, rowsum);
  nt_finalize <<<dim3(1),      256, 0, stream>>>(rowsum, posl, out);
}

// Round 6
// 60.677 us; speedup vs baseline: 1.6388x; 1.3193x over previous
//
#include <hip/hip_runtime.h>
#include <hip/hip_bf16.h>
#include <math.h>

#define B_  4096u
#define N_  8192
#define D_  128
#define M_  8190u          // negatives per logits row = 2B-2
#define SB_ 25159680u      // S_B = B*(2B-2) - B*(B-1)/2
#define NT2_ 1056          // upper-tri 128x256 tiles

#define AS1 __attribute__((address_space(1)))
#define AS3 __attribute__((address_space(3)))

typedef __attribute__((ext_vector_type(8))) short bf16x8;
typedef __attribute__((ext_vector_type(4))) float f32x4;
typedef __attribute__((ext_vector_type(4))) short short4v;

static __device__ __forceinline__ short f2b(float x) {
  __hip_bfloat16 h = __float2bfloat16(x);
  union { __hip_bfloat16 h; short s; } u; u.h = h; return u.s;
}
// cumulative flat-count of strict-upper (minus positives) elements before row i
static __device__ __forceinline__ unsigned rowS(unsigned i) {
  if (i <= B_) return i * (2u * B_ - 2u) - (i * (i - 1u)) / 2u;
  unsigned d = i - B_;
  return SB_ + d * (B_ - 1u) - (d * (d - 1u)) / 2u;
}
// cumulative tile count before row-panel m (128-row panels, 256-col tiles)
static __device__ __forceinline__ int tile0(int m) {
  return 32 * m - (m * m - 2 * m + (m & 1)) / 4;
}

// ---------------------------------------------------------------------------
// Kernel A: normalize rows of reps=[zjs;zis] -> bf16 nb[row][k]; build Trow;
// block 0 zeroes E buckets + completion counter (re-done every call: replay-safe).
// ---------------------------------------------------------------------------
__global__ __launch_bounds__(256) void nt_norm(
    const float* __restrict__ zis, const float* __restrict__ zjs,
    short* __restrict__ nb, unsigned* __restrict__ Trow,
    float* __restrict__ E, unsigned* __restrict__ counter) {
  const int t   = threadIdx.x;
  const int row = blockIdx.x * 8 + (t >> 5);
  const int c   = t & 31;
  const float* src = (row < (int)B_) ? (zjs + (size_t)row * D_)
                                     : (zis + (size_t)(row - (int)B_) * D_);
  float4 v = *(const float4*)(src + c * 4);
  float s = v.x * v.x + v.y * v.y + v.z * v.z + v.w * v.w;
  #pragma unroll
  for (int m = 16; m >= 1; m >>= 1) s += __shfl_xor(s, m, 32);
  float rn = 1.0f / fmaxf(sqrtf(s), 1e-8f);
  short4v o;
  o[0] = f2b(v.x * rn); o[1] = f2b(v.y * rn);
  o[2] = f2b(v.z * rn); o[3] = f2b(v.w * rn);
  *(short4v*)(nb + (size_t)row * D_ + c * 4) = o;

  if (t < 8) {
    unsigned i   = (unsigned)(blockIdx.x * 8 + t);
    unsigned S   = rowS(i);
    unsigned rlo = S / M_;
    unsigned Sh  = (rlo + 1u) * M_;
    unsigned jt  = Sh - S + i + 1u;
    Trow[i] = jt + ((i < B_ && jt > i + B_) ? 1u : 0u);
  }
  if (blockIdx.x == 0) {
    for (int r = t; r < 4112; r += 256) E[r] = 0.f;
    if (t == 0) *counter = 0u;
  }
}

// ---------------------------------------------------------------------------
// Kernel B: 128x256-tile upper-tri Gram, bf16 MFMA, 8 waves (2x4).
// K=128 as 4 phases of BK=32, DOUBLE-BUFFERED LDS via global_load_lds(16B),
// counted s_waitcnt vmcnt(3) + raw s_barrier (prefetch in flight across
// barriers). Both-sides XOR swizzle: slot ^= (row>>1)&3. Epilogue as R5.
// ---------------------------------------------------------------------------
__global__ __launch_bounds__(512, 4) void nt_gemm(
    const short* __restrict__ nb, const unsigned* __restrict__ Trow,
    float2* __restrict__ part, float* __restrict__ posl) {
  // XCD-chunked bijective swizzle: 1056 = 8 * 132
  const int tb = ((int)blockIdx.x & 7) * 132 + ((int)blockIdx.x >> 3);
  int bi2 = (int)(2.0f * (32.0f - sqrtf(fmaxf(0.f, 1024.0f - (float)tb))));
  if (bi2 > 63) bi2 = 63;
  while (bi2 > 0 && tb < tile0(bi2)) --bi2;
  while (tb >= tile0(bi2 + 1)) ++bi2;
  const int jlo = bi2 >> 1;
  const int bj2 = jlo + (tb - tile0(bi2));

  __shared__ short As[2][128 * 32];     // 2 x 8KB
  __shared__ short Bs[2][256 * 32];     // 2 x 16KB
  __shared__ float2 red2[4][128];       // 4KB          total 52KB

  const int t    = threadIdx.x;
  const int lane = t & 63, wave = t >> 6;
  const int li   = lane & 15, hi = lane >> 4;
  const int wr   = wave >> 2, wc = wave & 3;   // 2x4 wave grid
  const int i0   = bi2 * 128, j0 = bj2 * 256;

  const short* gA = nb + (size_t)i0 * D_;
  const short* gB = nb + (size_t)j0 * D_;

  // ---- stage phase 0 into buffer 0 ----
  {
    int e = t, r = e >> 2, sl = e & 3, sg = sl ^ ((r >> 1) & 3);
    __builtin_amdgcn_global_load_lds(
        (const AS1 void*)(gA + (size_t)r * D_ + sg * 8),
        (AS3 void*)(&As[0][e * 8]), 16, 0, 0);
  }
  #pragma unroll
  for (int it = 0; it < 2; ++it) {
    int e = it * 512 + t, r = e >> 2, sl = e & 3, sg = sl ^ ((r >> 1) & 3);
    __builtin_amdgcn_global_load_lds(
        (const AS1 void*)(gB + (size_t)r * D_ + sg * 8),
        (AS3 void*)(&Bs[0][e * 8]), 16, 0, 0);
  }

  f32x4 acc[4][4];
  #pragma unroll
  for (int m = 0; m < 4; ++m)
    #pragma unroll
    for (int n = 0; n < 4; ++n) acc[m][n] = (f32x4){0.f, 0.f, 0.f, 0.f};

  const int sw = hi ^ ((li >> 1) & 3);   // swizzled 16B slot for ds_read

  #pragma unroll
  for (int ph = 0; ph < 4; ++ph) {
    if (ph < 3) {   // prefetch phase ph+1 into the other buffer
      const int pb = (ph + 1) & 1, ko = (ph + 1) * 32;
      {
        int e = t, r = e >> 2, sl = e & 3, sg = sl ^ ((r >> 1) & 3);
        __builtin_amdgcn_global_load_lds(
            (const AS1 void*)(gA + (size_t)r * D_ + ko + sg * 8),
            (AS3 void*)(&As[pb][e * 8]), 16, 0, 0);
      }
      #pragma unroll
      for (int it = 0; it < 2; ++it) {
        int e = it * 512 + t, r = e >> 2, sl = e & 3, sg = sl ^ ((r >> 1) & 3);
        __builtin_amdgcn_global_load_lds(
            (const AS1 void*)(gB + (size_t)r * D_ + ko + sg * 8),
            (AS3 void*)(&Bs[pb][e * 8]), 16, 0, 0);
      }
      asm volatile("s_waitcnt vmcnt(3)" ::: "memory");  // phase ph landed
    } else {
      asm volatile("s_waitcnt vmcnt(0)" ::: "memory");
    }
    __builtin_amdgcn_s_barrier();
    __builtin_amdgcn_sched_barrier(0);

    const int cb = ph & 1;
    bf16x8 af[4], bfr[4];
    #pragma unroll
    for (int m = 0; m < 4; ++m)
      af[m] = *(const bf16x8*)(&As[cb][(wr * 64 + m * 16 + li) * 32 + sw * 8]);
    #pragma unroll
    for (int n = 0; n < 4; ++n)
      bfr[n] = *(const bf16x8*)(&Bs[cb][(wc * 64 + n * 16 + li) * 32 + sw * 8]);
    #pragma unroll
    for (int m = 0; m < 4; ++m)
      #pragma unroll
      for (int n = 0; n < 4; ++n)
        acc[m][n] = __builtin_amdgcn_mfma_f32_16x16x32_bf16(
            af[m], bfr[n], acc[m][n], 0, 0, 0);
    __builtin_amdgcn_s_barrier();   // all waves done reading buf cb
  }

  // ---- epilogue: threshold-bucket sums, shfl reduce, cross-wave combine ----
  const bool isdiag = (bj2 == jlo);
  const bool ispost = (bj2 == jlo + 16);
  const unsigned jw0 = (unsigned)(j0 + wc * 64);

  #pragma unroll
  for (int m = 0; m < 4; ++m) {
    const uint4 T4 = *(const uint4*)(Trow + i0 + wr * 64 + m * 16 + hi * 4);
    const unsigned Ts[4] = {T4.x, T4.y, T4.z, T4.w};
    #pragma unroll
    for (int rg = 0; rg < 4; ++rg) {
      const unsigned i = (unsigned)(i0 + wr * 64 + m * 16 + hi * 4 + rg);
      const unsigned T = Ts[rg];
      float s0 = 0.f, s1 = 0.f;
      if (isdiag | ispost) {
        #pragma unroll
        for (int n = 0; n < 4; ++n) {
          const unsigned j = jw0 + n * 16 + (unsigned)li;
          const bool ip = ispost && (j == i + B_);
          if (ip) posl[i] = 2.0f * acc[m][n][rg];
          if ((j > i) && !ip) {
            float e = __expf(2.0f * acc[m][n][rg]);
            if (j < T) s0 += e; else s1 += e;
          }
        }
      } else if ((T > jw0) && (T < jw0 + 64u)) {   // straddle (rare)
        #pragma unroll
        for (int n = 0; n < 4; ++n) {
          const unsigned j = jw0 + n * 16 + (unsigned)li;
          float e = __expf(2.0f * acc[m][n][rg]);
          if (j < T) s0 += e; else s1 += e;
        }
      } else {                                      // uniform bucket
        float s = 0.f;
        #pragma unroll
        for (int n = 0; n < 4; ++n) s += __expf(2.0f * acc[m][n][rg]);
        if (T > jw0) s0 = s; else s1 = s;
      }
      #pragma unroll
      for (int msk = 8; msk >= 1; msk >>= 1) {
        s0 += __shfl_xor(s0, msk, 16);
        s1 += __shfl_xor(s1, msk, 16);
      }
      if (li == 0)
        red2[wc][wr * 64 + m * 16 + hi * 4 + rg] = make_float2(s0, s1);
    }
  }
  __syncthreads();

  if (t < 128) {
    float2 s = make_float2(0.f, 0.f);
    #pragma unroll
    for (int w = 0; w < 4; ++w) {
      float2 v = red2[w][t];
      s.x += v.x; s.y += v.y;
    }
    part[(size_t)tb * 128 + t] = s;
  }
}

// ---------------------------------------------------------------------------
// Kernel C: fused rowreduce + finalize. 64 blocks; per-block: reduce partials
// for its 128-row panel, bucket-add into global E (16K spread atomics total);
// LAST block (fence+counter) computes the loss.
// ---------------------------------------------------------------------------
__global__ __launch_bounds__(256) void nt_rowfin(
    const float2* __restrict__ part, const float* __restrict__ posl,
    float* __restrict__ E, unsigned* __restrict__ counter,
    float* __restrict__ out) {
  __shared__ float2 xch[128];
  __shared__ int lastflag;
  __shared__ double red[256];
  const int bi2 = (int)blockIdx.x;             // 0..63 == row panel
  const int t = threadIdx.x;
  const int lrow = t & 127, sh = t >> 7;
  const int base = tile0(bi2);
  const int cnt  = 32 - (bi2 >> 1);

  float2 s = make_float2(0.f, 0.f);
  for (int c = sh; c < cnt; c += 2) {
    float2 v = part[(size_t)(base + c) * 128 + lrow];
    s.x += v.x; s.y += v.y;
  }
  if (sh == 1) xch[lrow] = s;
  __syncthreads();
  if (sh == 0) {
    float2 v = xch[lrow];
    s.x += v.x; s.y += v.y;
    const unsigned i   = (unsigned)(bi2 * 128 + lrow);
    const unsigned rlo = rowS(i) / M_;
    atomicAdd(&E[rlo],      s.x);
    atomicAdd(&E[rlo + 1u], s.y);
  }
  __threadfence();
  __syncthreads();
  if (t == 0) lastflag = (atomicAdd(counter, 1u) == 63u) ? 1 : 0;
  __syncthreads();
  if (!lastflag) return;

  // ---- last block: loss = (1/B) * sum_r ( log(exp(posl)+E[r]) - posl[r] )
  __threadfence();
  double acc = 0.0;
  for (int r = t; r < (int)B_; r += 256) {
    float ev = atomicAdd(&E[r], 0.0f);      // coherent read
    float pl = posl[r];
    acc += (double)(logf(__expf(pl) + ev) - pl);
  }
  red[t] = acc;
  __syncthreads();
  for (int m = 128; m > 0; m >>= 1) {
    if (t < m) red[t] += red[t + m];
    __syncthreads();
  }
  if (t == 0) out[0] = (float)(red[0] / (double)B_);
}

// ---------------------------------------------------------------------------
extern "C" void kernel_launch(void* const* d_in, const int* in_sizes, int n_in,
                              void* d_out, int out_size, void* d_ws, size_t ws_size,
                              hipStream_t stream) {
  const float* zis = (const float*)d_in[0];
  const float* zjs = (const float*)d_in[1];
  float* out = (float*)d_out;

  char* ws = (char*)d_ws;
  short*    nb      = (short*)ws;                          // 2 MB
  unsigned* Trow    = (unsigned*)(ws + 2097152);           // 32 KB
  float*    posl    = (float*)(ws + 2129920);              // 16 KB
  float2*   part    = (float2*)(ws + 2146304);             // 1.08 MB
  float*    E       = (float*)(ws + 3227648);              // 4112 floats
  unsigned* counter = (unsigned*)(ws + 3244096);           // 4 B

  nt_norm  <<<dim3(N_ / 8), 256, 0, stream>>>(zis, zjs, nb, Trow, E, counter);
  nt_gemm  <<<dim3(NT2_),   512, 0, stream>>>(nb, Trow, part, posl);
  nt_rowfin<<<dim3(64),     256, 0, stream>>>(part, posl, E, counter, out);
}